// Round 1
// baseline (18963.747 us; speedup 1.0000x reference)
//
#include <hip/hip_runtime.h>
#include <math.h>

#define TID ((int)threadIdx.x)
#define BID ((int)blockIdx.x)

typedef float4 f4;

// ---- dims ----
constexpr int NB   = 16;    // batch
constexpr int TENC = 384;
constexpr int TDEC = 200;
constexpr int HD   = 256;
constexpr int MELD = 400;
constexpr int P2   = 128;
constexpr int G3   = 768;

// ---- ws layout (float offsets) ----
constexpr int OFF_PM     = 0;                      // [16][384][256]
constexpr int OFF_GIPN   = OFF_PM     + NB*TENC*HD;    // [200][768][16]
constexpr int OFF_PN1    = OFF_GIPN   + TDEC*G3*NB;    // [200][256][16]
constexpr int OFF_PN2    = OFF_PN1    + TDEC*HD*NB;    // [200][128][16]
constexpr int OFF_D2O    = OFF_PN2    + TDEC*P2*NB;    // [200][256][16]
constexpr int OFF_ATTNH  = OFF_D2O    + TDEC*HD*NB;    // [2][256][16]
constexpr int OFF_CTX    = OFF_ATTNH  + 2*4096;        // [3][256][16] partial contexts
constexpr int OFF_D1     = OFF_CTX    + 3*4096;        // [2][256][16]
constexpr int OFF_D2     = OFF_D1     + 2*4096;        // [256][16]
constexpr int OFF_DECIN  = OFF_D2     + 4096;          // [256][16]
constexpr int OFF_DECIN1 = OFF_DECIN  + 4096;          // [256][16]
constexpr int OFF_GI     = OFF_DECIN1 + 4096;          // [768][16]
constexpr int OFF_GH     = OFF_GI     + 12288;
constexpr int OFF_GI1    = OFF_GH     + 12288;
constexpr int OFF_GH1    = OFF_GI1    + 12288;
constexpr int OFF_GI2    = OFF_GH1    + 12288;
constexpr int OFF_GH2    = OFF_GI2    + 12288;
constexpr int OFF_PQ     = OFF_GH2    + 12288;         // [16][256] b-major
constexpr int OFF_E      = OFF_PQ     + 4096;          // [16][384]
constexpr int OFF_W1T    = OFF_E      + 6144;          // [400][256]
constexpr int OFF_W2T    = OFF_W1T    + 102400;        // [256][128]
constexpr int OFF_WMEMT  = OFF_W2T    + 32768;         // [256][256]
constexpr int OFF_WPNT   = OFF_WMEMT  + 65536;         // [128][768]
constexpr int OFF_WATTT  = OFF_WPNT   + 98304;         // [256][768]
constexpr int OFF_WHHT   = OFF_WATTT  + 196608;        // [256][768]
constexpr int OFF_WQT    = OFF_WHHT   + 196608;        // [256][256]
constexpr int OFF_WPROJT = OFF_WQT    + 65536;         // [512][256]
constexpr int OFF_WIH1T  = OFF_WPROJT + 131072;        // [256][768]
constexpr int OFF_WHH1T  = OFF_WIH1T  + 196608;
constexpr int OFF_WIH2T  = OFF_WHH1T  + 196608;
constexpr int OFF_WHH2T  = OFF_WIH2T  + 196608;
constexpr int OFF_WMELT  = OFF_WHH2T  + 196608;        // [256][400]

__device__ __forceinline__ float sigf(float x){ return 1.f/(1.f+__expf(-x)); }
__device__ __forceinline__ float tanhf_(float x){
  x = fminf(15.f, fmaxf(-15.f, x));
  float e = __expf(2.f*x);
  return (e-1.f)/(e+1.f);
}

// ---------- init: zero recurrent state + ctx partials ----------
__global__ void k_init(float* ws){
  int g = BID*256 + TID;
  for (int idx = g; idx < 32768; idx += 32*256) ws[OFF_ATTNH + idx] = 0.f;
}

// ---------- transpose all weight matrices to k-major ----------
__global__ void k_tr(const float* pw1, const float* pw2, const float* wmem,
                     const float* gwih, const float* gwhh, const float* qw,
                     const float* pjw, const float* dwih, const float* dwhh,
                     const float* mw, float* ws){
  int g = BID*256 + TID;
  if (g < 102400){ int j=g%256,k=g/256; ws[OFF_W1T+g]=pw1[j*400+k]; return;} g-=102400;
  if (g < 32768){ int j=g%128,k=g/128; ws[OFF_W2T+g]=pw2[j*256+k]; return;} g-=32768;
  if (g < 65536){ int j=g%256,k=g/256; ws[OFF_WMEMT+g]=wmem[j*256+k]; return;} g-=65536;
  if (g < 98304){ int j=g%768,k=g/768; ws[OFF_WPNT+g]=gwih[j*384+k]; return;} g-=98304;
  if (g < 196608){ int j=g%768,k=g/768; ws[OFF_WATTT+g]=gwih[j*384+128+k]; return;} g-=196608;
  if (g < 196608){ int j=g%768,k=g/768; ws[OFF_WHHT+g]=gwhh[j*256+k]; return;} g-=196608;
  if (g < 65536){ int j=g%256,k=g/256; ws[OFF_WQT+g]=qw[j*256+k]; return;} g-=65536;
  if (g < 131072){ int j=g%256,k=g/256; ws[OFF_WPROJT+g]=pjw[j*512+k]; return;} g-=131072;
  if (g < 196608){ int j=g%768,k=g/768; ws[OFF_WIH1T+g]=dwih[j*256+k]; return;} g-=196608;
  if (g < 196608){ int j=g%768,k=g/768; ws[OFF_WHH1T+g]=dwhh[j*256+k]; return;} g-=196608;
  if (g < 196608){ int j=g%768,k=g/768; ws[OFF_WIH2T+g]=dwih[196608+j*256+k]; return;} g-=196608;
  if (g < 196608){ int j=g%768,k=g/768; ws[OFF_WHH2T+g]=dwhh[196608+j*256+k]; return;} g-=196608;
  if (g < 102400){ int j=g%400,k=g/400; ws[OFF_WMELT+g]=mw[j*256+k]; return;}
}

// ---------- processed_memory = enc @ mem_w^T ----------
__global__ void k_pm(const float* __restrict__ enc, float* __restrict__ ws){
  int b = BID / 24, t0 = (BID % 24) * 16;
  int d = TID;
  const float* W = ws + OFF_WMEMT + d;
  const float* A = enc + (size_t)(b*TENC + t0)*HD;
  float acc[16];
  #pragma unroll
  for (int tt=0; tt<16; ++tt) acc[tt]=0.f;
  for (int k=0; k<HD; k+=4){
    float w0=W[(k+0)*256], w1=W[(k+1)*256], w2=W[(k+2)*256], w3=W[(k+3)*256];
    #pragma unroll
    for (int tt=0; tt<16; ++tt){
      f4 a = *(const f4*)(A + tt*HD + k);
      acc[tt] += w0*a.x + w1*a.y + w2*a.z + w3*a.w;
    }
  }
  float* P = ws + OFF_PM + (size_t)(b*TENC + t0)*HD + d;
  #pragma unroll
  for (int tt=0; tt<16; ++tt) P[tt*HD] = acc[tt];
}

// ---------- prenet layer1 (all steps) ----------
__global__ void k_pre1(const float* __restrict__ inp, const float* __restrict__ pb1, float* __restrict__ ws){
  int t = BID >> 2;
  int j = ((BID & 3) * 64) + (TID & 63);
  int bq = TID >> 6;
  float b = pb1[j];
  float a0=b,a1=b,a2=b,a3=b;
  if (t > 0){
    const float* W = ws + OFF_W1T + j;
    const float* x0 = inp + (size_t)((bq*4+0)*TDEC + (t-1))*MELD;
    const float* x1 = inp + (size_t)((bq*4+1)*TDEC + (t-1))*MELD;
    const float* x2 = inp + (size_t)((bq*4+2)*TDEC + (t-1))*MELD;
    const float* x3 = inp + (size_t)((bq*4+3)*TDEC + (t-1))*MELD;
    for (int k=0;k<MELD;k+=4){
      float w0=W[(k+0)*256],w1=W[(k+1)*256],w2=W[(k+2)*256],w3=W[(k+3)*256];
      f4 v0=*(const f4*)(x0+k), v1=*(const f4*)(x1+k), v2=*(const f4*)(x2+k), v3=*(const f4*)(x3+k);
      a0 += w0*v0.x+w1*v0.y+w2*v0.z+w3*v0.w;
      a1 += w0*v1.x+w1*v1.y+w2*v1.z+w3*v1.w;
      a2 += w0*v2.x+w1*v2.y+w2*v2.z+w3*v2.w;
      a3 += w0*v3.x+w1*v3.y+w2*v3.z+w3*v3.w;
    }
  }
  f4 r; r.x=fmaxf(a0,0.f); r.y=fmaxf(a1,0.f); r.z=fmaxf(a2,0.f); r.w=fmaxf(a3,0.f);
  *(f4*)(ws + OFF_PN1 + (size_t)(t*HD + j)*NB + bq*4) = r;
}

// ---------- prenet layer2 ----------
__global__ void k_pre2(const float* __restrict__ pb2, float* __restrict__ ws){
  int t = BID >> 1;
  int j = ((BID & 1) * 64) + (TID & 63);
  int bq = TID >> 6;
  float b = pb2[j];
  f4 acc = {b,b,b,b};
  const float* W = ws + OFF_W2T + j;
  const float* A = ws + OFF_PN1 + (size_t)t*HD*NB + bq*4;
  #pragma unroll 4
  for (int k=0;k<HD;++k){
    float w = W[k*P2];
    f4 a = *(const f4*)(A + k*NB);
    acc.x += w*a.x; acc.y += w*a.y; acc.z += w*a.z; acc.w += w*a.w;
  }
  f4 r; r.x=fmaxf(acc.x,0.f); r.y=fmaxf(acc.y,0.f); r.z=fmaxf(acc.z,0.f); r.w=fmaxf(acc.w,0.f);
  *(f4*)(ws + OFF_PN2 + (size_t)(t*P2 + j)*NB + bq*4) = r;
}

// ---------- gipn = bih + pn2 @ wih[:, :128]^T  (all steps) ----------
__global__ void k_gipn(const float* __restrict__ gbih, float* __restrict__ ws){
  int t = BID / 12;
  int j = (BID % 12)*64 + (TID & 63);
  int bq = TID >> 6;
  float b = gbih[j];
  f4 acc = {b,b,b,b};
  const float* W = ws + OFF_WPNT + j;
  const float* A = ws + OFF_PN2 + (size_t)t*P2*NB + bq*4;
  #pragma unroll 4
  for (int k=0;k<P2;++k){
    float w = W[k*G3];
    f4 a = *(const f4*)(A + k*NB);
    acc.x += w*a.x; acc.y += w*a.y; acc.z += w*a.z; acc.w += w*a.w;
  }
  *(f4*)(ws + OFF_GIPN + (size_t)(t*G3 + j)*NB + bq*4) = acc;
}

// ---------- step kernel 1: gi/gh dots (attn GRU) + proj(i-1) + gh2 dots ----------
__global__ void k1(float* __restrict__ ws, const float* __restrict__ gbhh,
                   const float* __restrict__ pjb, const float* __restrict__ dbhh, int i){
  __shared__ float as[4096];
  int lane = TID & 63, bq = TID >> 6;
  if (BID < 12){                      // gi dots: watt^T . attention(i-1)
    if (i >= TDEC) return;
    const float* cp = ws + OFF_CTX;
    #pragma unroll
    for (int e=0;e<16;++e){ int id = TID + e*256; as[id] = cp[id] + cp[id+4096] + cp[id+8192]; }
    __syncthreads();
    int j = BID*64 + lane;
    f4 acc = *(const f4*)(ws + OFF_GIPN + ((size_t)i*G3 + j)*NB + bq*4);
    const float* W = ws + OFF_WATTT + j;
    #pragma unroll 4
    for (int k=0;k<HD;++k){
      float w = W[k*G3];
      f4 a = *(const f4*)&as[k*NB + bq*4];
      acc.x += w*a.x; acc.y += w*a.y; acc.z += w*a.z; acc.w += w*a.w;
    }
    *(f4*)(ws + OFF_GI + j*NB + bq*4) = acc;
  } else if (BID < 24){               // gh dots: whh^T . h(i-1) + bhh
    if (i >= TDEC) return;
    int j = (BID-12)*64 + lane;
    float bb = gbhh[j];
    f4 acc = {bb,bb,bb,bb};
    const float* W = ws + OFF_WHHT + j;
    const float* A = ws + OFF_ATTNH + ((i+1)&1)*4096 + bq*4;
    #pragma unroll 4
    for (int k=0;k<HD;++k){
      float w = W[k*G3];
      f4 a = *(const f4*)(A + k*NB);
      acc.x += w*a.x; acc.y += w*a.y; acc.z += w*a.z; acc.w += w*a.w;
    }
    *(f4*)(ws + OFF_GH + j*NB + bq*4) = acc;
  } else if (BID < 28){               // proj_to_decoder_in for step i-1
    if (i == 0) return;
    const float* cp = ws + OFF_CTX;
    #pragma unroll
    for (int e=0;e<16;++e){ int id = TID + e*256; as[id] = cp[id] + cp[id+4096] + cp[id+8192]; }
    __syncthreads();
    int row = (BID-24)*64 + lane;
    float bb = pjb[row];
    f4 acc = {bb,bb,bb,bb};
    const float* W = ws + OFF_WPROJT + row;
    const float* Ah = ws + OFF_ATTNH + ((i+1)&1)*4096 + bq*4;
    #pragma unroll 4
    for (int k=0;k<HD;++k){
      float w = W[k*HD];
      f4 a = *(const f4*)(Ah + k*NB);
      acc.x += w*a.x; acc.y += w*a.y; acc.z += w*a.z; acc.w += w*a.w;
    }
    #pragma unroll 4
    for (int k=0;k<HD;++k){
      float w = W[(k+HD)*HD];
      f4 a = *(const f4*)&as[k*NB + bq*4];
      acc.x += w*a.x; acc.y += w*a.y; acc.z += w*a.z; acc.w += w*a.w;
    }
    *(f4*)(ws + OFF_DECIN + row*NB + bq*4) = acc;
  } else if (BID < 40){               // gh2 = bhh2 + whh2^T . d2(i-2)
    if (i == 0) return;
    int j = (BID-28)*64 + lane;
    float bb = dbhh[G3 + j];
    f4 acc = {bb,bb,bb,bb};
    const float* W = ws + OFF_WHH2T + j;
    const float* A = ws + OFF_D2 + bq*4;
    #pragma unroll 4
    for (int k=0;k<HD;++k){
      float w = W[k*G3];
      f4 a = *(const f4*)(A + k*NB);
      acc.x += w*a.x; acc.y += w*a.y; acc.z += w*a.z; acc.w += w*a.w;
    }
    *(f4*)(ws + OFF_GH2 + j*NB + bq*4) = acc;
  }
}

// ---------- step kernel 2: attn-GRU gates + pq dots; D1 gi dots ----------
__global__ void k2(float* __restrict__ ws, const float* __restrict__ dbih, int i){
  __shared__ float attns[4096];
  int lane = TID & 63, bq = TID >> 6;
  if (BID < 4){
    if (i >= TDEC) return;
    const float* gi = ws + OFF_GI; const float* gh = ws + OFF_GH;
    const float* hp = ws + OFF_ATTNH + ((i+1)&1)*4096;
    float* hn = ws + OFF_ATTNH + (i&1)*4096;
    #pragma unroll
    for (int e=0;e<16;++e){
      int id = TID + e*256;
      float ir=gi[id], iz=gi[id+4096], in_=gi[id+8192];
      float hr=gh[id], hz=gh[id+4096], hnn=gh[id+8192];
      float h = hp[id];
      float rr = sigf(ir+hr), zz = sigf(iz+hz);
      float nn = tanhf_(in_ + rr*hnn);
      float v = (1.f-zz)*nn + zz*h;
      attns[id] = v;
      if (BID==0) hn[id] = v;
    }
    __syncthreads();
    int row = BID*64 + lane;
    const float* W = ws + OFF_WQT + row;
    float a0=0.f,a1=0.f,a2=0.f,a3=0.f;
    #pragma unroll 4
    for (int k=0;k<HD;++k){
      float w = W[k*HD];
      f4 a = *(const f4*)&attns[k*NB + bq*4];
      a0 += w*a.x; a1 += w*a.y; a2 += w*a.z; a3 += w*a.w;
    }
    float* pq = ws + OFF_PQ;
    pq[(bq*4+0)*HD+row]=a0; pq[(bq*4+1)*HD+row]=a1;
    pq[(bq*4+2)*HD+row]=a2; pq[(bq*4+3)*HD+row]=a3;
  } else {                            // gi1 = bih1 + wih1^T . dec_in(i-1)
    if (i == 0) return;
    int j = (BID-4)*64 + lane;
    float bb = dbih[j];
    f4 acc = {bb,bb,bb,bb};
    const float* W = ws + OFF_WIH1T + j;
    const float* A = ws + OFF_DECIN + bq*4;
    #pragma unroll 4
    for (int k=0;k<HD;++k){
      float w = W[k*G3];
      f4 a = *(const f4*)(A + k*NB);
      acc.x += w*a.x; acc.y += w*a.y; acc.z += w*a.z; acc.w += w*a.w;
    }
    *(f4*)(ws + OFF_GI1 + j*NB + bq*4) = acc;
  }
}

// ---------- step kernel 4: energies; D1 gates (recomputed) + D2 gi dots ----------
__global__ void k4(float* __restrict__ ws, const float* __restrict__ av,
                   const int* __restrict__ mlen, const float* __restrict__ dbih, int i){
  __shared__ float sh[4096];
  if (BID < 48){
    if (i >= TDEC) return;
    int b = BID/3, ts = BID%3;
    int ks = TID >> 7, tt = TID & 127;
    int t = ts*128 + tt;
    const float* pmr = ws + OFF_PM + (size_t)(b*TENC + t)*HD + ks*128;
    const float* pqb = ws + OFF_PQ + b*HD + ks*128;
    const float* vv = av + ks*128;
    float s = 0.f;
    #pragma unroll 4
    for (int d=0; d<128; d+=4){
      f4 p = *(const f4*)(pmr+d);
      f4 q = *(const f4*)(pqb+d);
      f4 w = *(const f4*)(vv+d);
      s += w.x*tanhf_(p.x+q.x) + w.y*tanhf_(p.y+q.y)
         + w.z*tanhf_(p.z+q.z) + w.w*tanhf_(p.w+q.w);
    }
    sh[TID] = s; __syncthreads();
    if (TID < 128){
      float e = sh[TID] + sh[TID+128];
      int len = mlen[b];
      int tw = ts*128 + TID;
      ws[OFF_E + b*TENC + tw] = (tw < len) ? e : -1e30f;
    }
  } else {
    if (i == 0) return;
    int lane = TID & 63, bq = TID >> 6;
    const float* gi1 = ws + OFF_GI1; const float* gh1 = ws + OFF_GH1;
    const float* d1p = ws + OFF_D1 + (i&1)*4096;
    float* d1n = ws + OFF_D1 + ((i+1)&1)*4096;
    const float* din = ws + OFF_DECIN;
    float* din1 = ws + OFF_DECIN1;
    #pragma unroll
    for (int e=0;e<16;++e){
      int id = TID + e*256;
      float ir=gi1[id], iz=gi1[id+4096], in_=gi1[id+8192];
      float hr=gh1[id], hz=gh1[id+4096], hnn=gh1[id+8192];
      float h = d1p[id];
      float rr=sigf(ir+hr), zz=sigf(iz+hz);
      float nn=tanhf_(in_+rr*hnn);
      float dn = (1.f-zz)*nn + zz*h;
      float v = dn + din[id];
      sh[id] = v;
      if (BID==48){ d1n[id]=dn; din1[id]=v; }
    }
    __syncthreads();
    int j = (BID-48)*64 + lane;
    float bb = dbih[G3 + j];
    f4 acc = {bb,bb,bb,bb};
    const float* W = ws + OFF_WIH2T + j;
    #pragma unroll 4
    for (int k=0;k<HD;++k){
      float w = W[k*G3];
      f4 a = *(const f4*)&sh[k*NB + bq*4];
      acc.x += w*a.x; acc.y += w*a.y; acc.z += w*a.z; acc.w += w*a.w;
    }
    *(f4*)(ws + OFF_GI2 + j*NB + bq*4) = acc;
  }
}

// ---------- step kernel 5: softmax+context(slice); D2 gates; gh1 dots ----------
__global__ void k5(float* __restrict__ ws, const float* __restrict__ enc,
                   const float* __restrict__ dbhh, float* __restrict__ out, int i){
  __shared__ float red[256];
  __shared__ float ps[128];
  if (BID < 48){
    if (i >= TDEC) return;
    int b = BID/3, ts = BID%3;
    const float* eb = ws + OFF_E + b*TENC;
    float m = -1e30f;
    for (int idx=TID; idx<TENC; idx+=256) m = fmaxf(m, eb[idx]);
    red[TID]=m; __syncthreads();
    for (int s=128; s>0; s>>=1){ if (TID<s) red[TID]=fmaxf(red[TID],red[TID+s]); __syncthreads(); }
    float M = red[0]; __syncthreads();
    float sl = 0.f;
    for (int idx=TID; idx<TENC; idx+=256) sl += __expf(eb[idx]-M);
    red[TID]=sl; __syncthreads();
    for (int s=128; s>0; s>>=1){ if (TID<s) red[TID]+=red[TID+s]; __syncthreads(); }
    float inv = 1.f/red[0];
    __syncthreads();
    if (TID < 128){
      int t = ts*128 + TID;
      float p = __expf(eb[t]-M)*inv;
      ps[TID] = p;
      out[1280000 + (size_t)(b*TDEC + i)*TENC + t] = p;
    }
    __syncthreads();
    const float* encb = enc + (size_t)(b*TENC + ts*128)*HD + TID;
    float ctx = 0.f;
    #pragma unroll 8
    for (int tt=0;tt<128;++tt) ctx += ps[tt]*encb[(size_t)tt*HD];
    ws[OFF_CTX + ts*4096 + TID*NB + b] = ctx;
  } else if (BID < 52){               // D2 gates for step i-1
    if (i == 0) return;
    const float* gi2 = ws+OFF_GI2; const float* gh2 = ws+OFF_GH2;
    float* d2 = ws+OFF_D2; const float* din1 = ws+OFF_DECIN1;
    float* d2o = ws + OFF_D2O + (size_t)(i-1)*4096;
    #pragma unroll
    for (int e=0;e<4;++e){
      int id = (BID-48)*1024 + e*256 + TID;
      float ir=gi2[id], iz=gi2[id+4096], in_=gi2[id+8192];
      float hr=gh2[id], hz=gh2[id+4096], hnn=gh2[id+8192];
      float h = d2[id];
      float rr=sigf(ir+hr), zz=sigf(iz+hz);
      float nn=tanhf_(in_+rr*hnn);
      float dn=(1.f-zz)*nn+zz*h;
      d2[id]=dn;
      d2o[id]=dn+din1[id];
    }
  } else {                            // gh1 = bhh1 + whh1^T . d1(i-1)
    if (i >= TDEC) return;
    int lane=TID&63, bq=TID>>6;
    int j = (BID-52)*64 + lane;
    float bb = dbhh[j];
    f4 acc = {bb,bb,bb,bb};
    const float* W = ws+OFF_WHH1T+j;
    const float* A = ws+OFF_D1+((i+1)&1)*4096+bq*4;
    #pragma unroll 4
    for (int k=0;k<HD;++k){
      float w = W[k*G3];
      f4 a = *(const f4*)(A + k*NB);
      acc.x += w*a.x; acc.y += w*a.y; acc.z += w*a.z; acc.w += w*a.w;
    }
    *(f4*)(ws + OFF_GH1 + j*NB + bq*4) = acc;
  }
}

// ---------- mel projection (all steps) ----------
__global__ void k_mel(const float* __restrict__ ws, const float* __restrict__ mb, float* __restrict__ out){
  int t = BID/7, rb = (BID%7)*64;
  int j = rb + (TID&63), bq = TID>>6;
  if (j >= MELD) return;
  float bb = mb[j];
  f4 acc = {bb,bb,bb,bb};
  const float* W = ws + OFF_WMELT + j;
  const float* A = ws + OFF_D2O + (size_t)t*4096 + bq*4;
  #pragma unroll 4
  for (int k=0;k<HD;++k){
    float w = W[k*MELD];
    f4 a = *(const f4*)(A + k*NB);
    acc.x += w*a.x; acc.y += w*a.y; acc.z += w*a.z; acc.w += w*a.w;
  }
  out[(size_t)(bq*4+0)*80000 + t*MELD + j] = acc.x;
  out[(size_t)(bq*4+1)*80000 + t*MELD + j] = acc.y;
  out[(size_t)(bq*4+2)*80000 + t*MELD + j] = acc.z;
  out[(size_t)(bq*4+3)*80000 + t*MELD + j] = acc.w;
}

extern "C" void kernel_launch(void* const* d_in, const int* in_sizes, int n_in,
                              void* d_out, int out_size, void* d_ws, size_t ws_size,
                              hipStream_t stream) {
  const float* enc  = (const float*)d_in[0];
  const float* inp  = (const float*)d_in[1];
  const int*   mlen = (const int*)  d_in[2];
  const float* pw1  = (const float*)d_in[3];
  const float* pb1  = (const float*)d_in[4];
  const float* pw2  = (const float*)d_in[5];
  const float* pb2  = (const float*)d_in[6];
  const float* wmem = (const float*)d_in[7];
  const float* gwih = (const float*)d_in[8];
  const float* gwhh = (const float*)d_in[9];
  const float* gbih = (const float*)d_in[10];
  const float* gbhh = (const float*)d_in[11];
  const float* qw   = (const float*)d_in[12];
  const float* av   = (const float*)d_in[13];
  const float* pjw  = (const float*)d_in[14];
  const float* pjb  = (const float*)d_in[15];
  const float* dwih = (const float*)d_in[16];
  const float* dwhh = (const float*)d_in[17];
  const float* dbih = (const float*)d_in[18];
  const float* dbhh = (const float*)d_in[19];
  const float* mw   = (const float*)d_in[20];
  const float* mb   = (const float*)d_in[21];
  float* ws  = (float*)d_ws;
  float* out = (float*)d_out;

  k_init<<<32,256,0,stream>>>(ws);
  k_tr  <<<6944,256,0,stream>>>(pw1,pw2,wmem,gwih,gwhh,qw,pjw,dwih,dwhh,mw,ws);
  k_pm  <<<384,256,0,stream>>>(enc, ws);
  k_pre1<<<800,256,0,stream>>>(inp, pb1, ws);
  k_pre2<<<400,256,0,stream>>>(pb2, ws);
  k_gipn<<<2400,256,0,stream>>>(gbih, ws);
  for (int i = 0; i <= TDEC; ++i){
    k1<<<40,256,0,stream>>>(ws, gbhh, pjb, dbhh, i);
    k2<<<16,256,0,stream>>>(ws, dbih, i);
    k4<<<60,256,0,stream>>>(ws, av, mlen, dbih, i);
    k5<<<64,256,0,stream>>>(ws, enc, dbhh, out, i);
  }
  k_mel<<<1400,256,0,stream>>>(ws, mb, out);
}